// Round 4
// baseline (256.315 us; speedup 1.0000x reference)
//
#include <hip/hip_runtime.h>

// Rotation by label: B=256, C=3, H=W=224 fp32.
//   lab 0: out[h][w] = in[h][w]
//   lab 1: out[h][w] = in[w][h]            (transpose)
//   lab 2: out[h][w] = in[223-h][w]        (flip rows)
//   lab 3: out[h][w] = in[223-w][h]        (transpose + flip cols)
//
// v4: 112x112 transpose tiles -> 448 B contiguous DRAM runs on BOTH sides of
// the transpose path (vs 128 B with 32x32 tiles). Block = 448 threads, one
// tile (quarter-plane) per block, exactly 7 f4/thread/phase.
//   - lab 0: quarter-plane linear f4 copy (50 KB contiguous)
//   - lab 2: 56-row band; rows whole, write side linear
//   - lab 1/3: load 112x112 tile (448 B runs) -> LDS transposed-scatter
//     (scalar, stride 113 -> ~4-way bank alias, cheap) -> row-linear LDS read
//     -> 448 B-run stores. One barrier per block. All 7 loads in flight first.
//   - nontemporal everywhere (pure streaming), label write fused into block 0.
// Label uniform per block -> no divergence.

#define HW 224
#define W4 56        // HW/4 f4 per row
#define TS 112       // transpose tile size
#define TQ4 28       // TS/4 f4 per tile row
#define LS 113       // LDS stride (floats); 4*113 mod 32 = 4 -> 8-bank spread

typedef float f4 __attribute__((ext_vector_type(4)));

__global__ __launch_bounds__(448) void rot4_kernel(const float* __restrict__ x,
                                                   const int* __restrict__ label,
                                                   float* __restrict__ out,
                                                   float* __restrict__ out_label,
                                                   int B) {
    const int t = threadIdx.x;

    // fused label write (second tuple element, as float)
    if (blockIdx.x == 0)
        for (int li = t; li < B; li += 448) out_label[li] = (float)label[li];

    int blk = blockIdx.x;
    const int q = blk & 3;  blk >>= 2;     // tile / quarter index 0..3
    const int c = blk % 3;
    const int b = blk / 3;

    const int lab = label[b];              // block-uniform
    const size_t plane = (size_t)(b * 3 + c) * (HW * HW);
    const float* in = x + plane;
    float*       o  = out + plane;

    if (lab == 0) {
        // quarter-plane: one contiguous run of 3136 f4
        const f4* in4 = (const f4*)in;
        f4*       o4  = (f4*)o;
        const int base = q * 3136;
        #pragma unroll
        for (int k = 0; k < 7; ++k) {
            int i = base + k * 448 + t;
            f4 v = __builtin_nontemporal_load(in4 + i);
            __builtin_nontemporal_store(v, o4 + i);
        }
    } else if (lab == 2) {
        // 56-row band [q*56, q*56+56); out row h = in row 223-h
        const f4* in4 = (const f4*)in;
        f4*       o4  = (f4*)o;
        #pragma unroll
        for (int k = 0; k < 7; ++k) {
            int idx = k * 448 + t;         // 0..3135 within band
            int rr  = idx / W4;            // row within band (0..55)
            int cc  = idx - rr * W4;       // f4 col (0..55)
            int row = q * W4 + rr;         // note: band height 56 == W4
            f4 v = __builtin_nontemporal_load(in4 + (size_t)(HW - 1 - row) * W4 + cc);
            __builtin_nontemporal_store(v, o4 + (size_t)row * W4 + cc);
        }
    } else {
        // transpose tile. Output tile (Ti,Tj): rows [Ri,Ri+112), cols [Cj,Cj+112)
        //   lab 1: <- in rows [Cj,+112), cols [Ri,+112);  out[r][u] = it[u][r]
        //   lab 3: <- in rows [112-Cj,+112), cols [Ri,+112); out[r][u] = it[111-u][r]
        // LDS layout trans(c,s) = it[s][c] at c*LS + s:
        //   writes: (4cq+j)*LS + s  -> 8-bank spread (~4-way), scalar
        //   reads:  r*LS + u        -> row-linear, conflict-free
        __shared__ float trans[TS * LS];
        const int g  = t / TQ4;            // 0..15 row group
        const int cq = t % TQ4;            // 0..27 f4 col
        const int Ti = q >> 1, Tj = q & 1;
        const int Ri = Ti * TS, Cj = Tj * TS;
        const int SR = (lab == 1) ? Cj : (TS - Cj);   // source row base
        const int SC = Ri;                             // source col base

        f4 v[7];
        #pragma unroll
        for (int p = 0; p < 7; ++p) {      // all 7 loads in flight (MLP 7)
            int s = p * 16 + g;
            v[p] = __builtin_nontemporal_load(
                (const f4*)(in + (size_t)(SR + s) * HW + SC + cq * 4));
        }
        #pragma unroll
        for (int p = 0; p < 7; ++p) {
            int s = p * 16 + g;
            trans[(cq * 4 + 0) * LS + s] = v[p].x;
            trans[(cq * 4 + 1) * LS + s] = v[p].y;
            trans[(cq * 4 + 2) * LS + s] = v[p].z;
            trans[(cq * 4 + 3) * LS + s] = v[p].w;
        }
        __syncthreads();
        #pragma unroll
        for (int p = 0; p < 7; ++p) {
            int r = p * 16 + g;
            const float* tr = &trans[r * LS];
            f4 w;
            if (lab == 1) {
                w.x = tr[cq * 4 + 0];
                w.y = tr[cq * 4 + 1];
                w.z = tr[cq * 4 + 2];
                w.w = tr[cq * 4 + 3];
            } else {
                w.x = tr[111 - (cq * 4 + 0)];
                w.y = tr[111 - (cq * 4 + 1)];
                w.z = tr[111 - (cq * 4 + 2)];
                w.w = tr[111 - (cq * 4 + 3)];
            }
            __builtin_nontemporal_store(
                w, (f4*)(o + (size_t)(Ri + r) * HW + Cj + cq * 4));
        }
    }
}

extern "C" void kernel_launch(void* const* d_in, const int* in_sizes, int n_in,
                              void* d_out, int out_size, void* d_ws, size_t ws_size,
                              hipStream_t stream) {
    const float* x     = (const float*)d_in[0];
    const int*   label = (const int*)d_in[1];
    float*       out   = (float*)d_out;

    const int B = in_sizes[1];                       // 256
    const int nblocks = B * 3 * 4;                   // one block per 112x112 tile
    const size_t img_elems = (size_t)B * 3 * HW * HW;

    rot4_kernel<<<nblocks, 448, 0, stream>>>(x, label, out, out + img_elems, B);
}

// Round 5
// 249.897 us; speedup vs baseline: 1.0257x; 1.0257x over previous
//
#include <hip/hip_runtime.h>

// Rotation by label: B=256, C=3, H=W=224 fp32.
//   lab 0: out[h][w] = in[h][w]
//   lab 1: out[h][w] = in[w][h]            (transpose)
//   lab 2: out[h][w] = in[223-h][w]        (flip rows)
//   lab 3: out[h][w] = in[223-w][h]        (transpose + flip cols)
//
// v5: revert to the v3 structure (best measured: 250.2 us) -- one block per
// 32-row band, 256 threads, 7 f4/thread, full register prefetch (MLP 7),
// nontemporal streaming, label write fused -- with one zero-cost tweak:
// 4 LDS tile buffers (16.9 KB, still 8 blocks/CU = 32 waves/CU) so the
// transpose path uses 3 barriers instead of 7, and stores issue in groups.
// v4's 112x112-tile experiment (448 B DRAM runs) regressed (+6 us): occupancy
// 21 waves/CU, 4-way LDS write conflicts, unaligned LDS reads. v3's stride-33
// 32x32 tiles are <=2-way (free) on both LDS sides, so the tile size stays.
// Label is uniform per block (depends only on b) -> no divergence.

#define HW 224
#define W4 56        // HW/4 float4 per row
#define TILE 32
#define NT 7         // 224 / 32

typedef float f4 __attribute__((ext_vector_type(4)));

__global__ __launch_bounds__(256) void rot4_kernel(const float* __restrict__ x,
                                                   const int* __restrict__ label,
                                                   float* __restrict__ out,
                                                   float* __restrict__ out_label,
                                                   int B) {
    const int t = threadIdx.x;

    // fused label write (second tuple element, as float)
    {
        int li = blockIdx.x * 256 + t;
        if (blockIdx.x < (B + 255) / 256 && li < B) out_label[li] = (float)label[li];
    }

    int blk = blockIdx.x;
    const int th = blk % NT; blk /= NT;    // band index (32 rows)
    const int c  = blk % 3;  blk /= 3;     // channel
    const int b  = blk;                    // batch

    const int lab = label[b];              // block-uniform
    const size_t plane = (size_t)(b * 3 + c) * (HW * HW);
    const float*  in = x + plane;
    float*        o  = out + plane;
    const f4* in4 = (const f4*)in;
    f4*       o4  = (f4*)o;
    const int h0 = th * TILE;

    if (lab == 0) {
        // band [h0, h0+32) is one contiguous run of 7*256 f4
        const size_t base = (size_t)h0 * W4;
        #pragma unroll
        for (int k = 0; k < NT; ++k) {
            size_t i = base + (size_t)k * 256 + t;
            f4 v = __builtin_nontemporal_load(in4 + i);
            __builtin_nontemporal_store(v, o4 + i);
        }
    } else if (lab == 2) {
        // out row h = in row 223-h; write side linear over the band
        #pragma unroll
        for (int k = 0; k < NT; ++k) {
            int idx = k * 256 + t;         // 0..1791 within band
            int rr  = idx / W4;            // row within band (0..31)
            int cc  = idx - rr * W4;       // float4 col (0..55)
            size_t src = (size_t)(HW - 1 - (h0 + rr)) * W4 + cc;
            size_t dst = (size_t)(h0 + rr) * W4 + cc;
            f4 v = __builtin_nontemporal_load(in4 + src);
            __builtin_nontemporal_store(v, o4 + dst);
        }
    } else {
        // transpose via LDS tiles; stride 33 -> bank (4c4+j+r)%32 -> <=2-way
        // (free on wave64) for both scatter-writes and gather-reads.
        // 4 buffers -> 3 barriers total (write 0-3 | read 0-3 | write 4-6 |
        // read 4-6). All 7 global loads prefetched to registers first.
        __shared__ float tb[4][TILE][TILE + 1];
        const int r  = t >> 3;             // 0..31 tile row
        const int c4 = t & 7;              // 0..7  float4 col within tile

        // source tile rows: lab==1 -> [w0, w0+32); lab==3 -> [192-w0, 224-w0)
        auto src_ptr = [&](int tw) {
            const int w0 = tw * TILE;
            const int rbase = (lab == 1) ? w0 : (HW - TILE - w0);
            return (const f4*)(in + (size_t)(rbase + r) * HW + h0 + c4 * 4);
        };

        f4 v[NT];
        #pragma unroll
        for (int k = 0; k < NT; ++k)
            v[k] = __builtin_nontemporal_load(src_ptr(k));

        auto stage = [&](int tw, int buf) {
            float (*tbuf)[TILE + 1] = tb[buf];
            tbuf[r][c4 * 4 + 0] = v[tw].x;
            tbuf[r][c4 * 4 + 1] = v[tw].y;
            tbuf[r][c4 * 4 + 2] = v[tw].z;
            tbuf[r][c4 * 4 + 3] = v[tw].w;
        };
        auto drain = [&](int tw, int buf) {
            float (*tbuf)[TILE + 1] = tb[buf];
            f4 w;
            if (lab == 1) {
                // out[h0+r][w0+4c4+j] = in[w0+4c4+j][h0+r] = tbuf[4c4+j][r]
                w.x = tbuf[c4 * 4 + 0][r];
                w.y = tbuf[c4 * 4 + 1][r];
                w.z = tbuf[c4 * 4 + 2][r];
                w.w = tbuf[c4 * 4 + 3][r];
            } else {
                // out[h0+r][w0+4c4+j] = in[223-w0-4c4-j][h0+r] = tbuf[31-4c4-j][r]
                w.x = tbuf[31 - (c4 * 4 + 0)][r];
                w.y = tbuf[31 - (c4 * 4 + 1)][r];
                w.z = tbuf[31 - (c4 * 4 + 2)][r];
                w.w = tbuf[31 - (c4 * 4 + 3)][r];
            }
            const int w0 = tw * TILE;
            __builtin_nontemporal_store(
                w, (f4*)(o + (size_t)(h0 + r) * HW + w0 + c4 * 4));
        };

        #pragma unroll
        for (int k = 0; k < 4; ++k) stage(k, k);
        __syncthreads();
        #pragma unroll
        for (int k = 0; k < 4; ++k) drain(k, k);
        __syncthreads();
        #pragma unroll
        for (int k = 4; k < 7; ++k) stage(k, k - 4);
        __syncthreads();
        #pragma unroll
        for (int k = 4; k < 7; ++k) drain(k, k - 4);
    }
}

extern "C" void kernel_launch(void* const* d_in, const int* in_sizes, int n_in,
                              void* d_out, int out_size, void* d_ws, size_t ws_size,
                              hipStream_t stream) {
    const float* x     = (const float*)d_in[0];
    const int*   label = (const int*)d_in[1];
    float*       out   = (float*)d_out;

    const int B = in_sizes[1];                       // 256
    const int nblocks = B * 3 * NT;                  // one block per 32-row band
    const size_t img_elems = (size_t)B * 3 * HW * HW;

    rot4_kernel<<<nblocks, 256, 0, stream>>>(x, label, out, out + img_elems, B);
}